// Round 10
// baseline (150.013 us; speedup 1.0000x reference)
//
#include <hip/hip_runtime.h>
#include <stdint.h>

#define Bsz  8192
#define DMOD 512
#define NE   4
#define NP   1024
#define NF   2048
#define BM   160
#define MAXTILES 57   // sum_b ceil(cnt_b/160) <= ceil(8192/160)+5 = 57

typedef float  f32x4  __attribute__((ext_vector_type(4)));
typedef __bf16 bf16x8 __attribute__((ext_vector_type(8)));
typedef unsigned short u16x8 __attribute__((ext_vector_type(8)));

typedef __attribute__((address_space(3))) void       lds_void;
typedef const __attribute__((address_space(1))) void glb_void;
#define GLOAD16(gp, lp) \
  __builtin_amdgcn_global_load_lds((glb_void*)(gp), (lds_void*)(lp), 16, 0, 0)

__device__ __forceinline__ unsigned short f32_bf16(float f) {
  unsigned int u = __float_as_uint(f);
  u += 0x7FFFu + ((u >> 16) & 1u);   // round-to-nearest-even
  return (unsigned short)(u >> 16);
}

// ---------------- kernel 1: gate + fusedB write (blocks 0..8191) | We transpose (rest) ------
__global__ __launch_bounds__(256) void gate_fuse(
    const float* __restrict__ x0, const float* __restrict__ x1,
    const float* __restrict__ x2, const float* __restrict__ x3,
    const float* __restrict__ Wg, const float* __restrict__ We,
    float* __restrict__ gw, int* __restrict__ pair,
    unsigned short* __restrict__ fusedB, unsigned short* __restrict__ WeT)
{
  __shared__ float sred[4][4];
  __shared__ float tsh[64][65];
  const int tid = threadIdx.x;

  if ((int)blockIdx.x < Bsz) {
    // ---- gate: logits -> softmax -> top2 -> gw + pair code; also emit bf16 row ----
    const int b = blockIdx.x;
    const int f = tid * 8;
    const float* xm  = (f < 1024) ? (f < 512 ? x0 : x1) : (f < 1536 ? x2 : x3);
    const float* src = xm + (size_t)b * DMOD + (f & 511);
    float4 v0 = *(const float4*)src;
    float4 v1 = *(const float4*)(src + 4);
    u16x8 o;
    o[0] = f32_bf16(v0.x); o[1] = f32_bf16(v0.y); o[2] = f32_bf16(v0.z); o[3] = f32_bf16(v0.w);
    o[4] = f32_bf16(v1.x); o[5] = f32_bf16(v1.y); o[6] = f32_bf16(v1.z); o[7] = f32_bf16(v1.w);
    *(u16x8*)(fusedB + (size_t)b * NF + f) = o;

    float d[4];
    #pragma unroll
    for (int e = 0; e < 4; ++e) {
      const float* w = Wg + e * NF + f;
      d[e] = v0.x * w[0] + v0.y * w[1] + v0.z * w[2] + v0.w * w[3]
           + v1.x * w[4] + v1.y * w[5] + v1.z * w[6] + v1.w * w[7];
    }
    #pragma unroll
    for (int off = 32; off; off >>= 1) {
      #pragma unroll
      for (int e = 0; e < 4; ++e) d[e] += __shfl_xor(d[e], off);
    }
    if ((tid & 63) == 0) {
      #pragma unroll
      for (int e = 0; e < 4; ++e) sred[tid >> 6][e] = d[e];
    }
    __syncthreads();
    if (tid == 0) {
      float a0 = sred[0][0] + sred[1][0] + sred[2][0] + sred[3][0];
      float a1 = sred[0][1] + sred[1][1] + sred[2][1] + sred[3][1];
      float a2 = sred[0][2] + sred[1][2] + sred[2][2] + sred[3][2];
      float a3 = sred[0][3] + sred[1][3] + sred[2][3] + sred[3][3];
      float m  = fmaxf(fmaxf(a0, a1), fmaxf(a2, a3));
      float e0 = expf(a0 - m), e1 = expf(a1 - m), e2 = expf(a2 - m), e3 = expf(a3 - m);
      float inv = 1.f / (e0 + e1 + e2 + e3);
      float p0 = e0 * inv, p1 = e1 * inv, p2 = e2 * inv, p3 = e3 * inv;
      int i1 = 0; float b1 = a0;                 // jax tie-break: strict >
      if (a1 > b1) { b1 = a1; i1 = 1; }
      if (a2 > b1) { b1 = a2; i1 = 2; }
      if (a3 > b1) { b1 = a3; i1 = 3; }
      int i2 = -1; float b2 = -3.4e38f;
      if (i1 != 0 && a0 > b2) { b2 = a0; i2 = 0; }
      if (i1 != 1 && a1 > b2) { b2 = a1; i2 = 1; }
      if (i1 != 2 && a2 > b2) { b2 = a2; i2 = 2; }
      if (i1 != 3 && a3 > b2) { b2 = a3; i2 = 3; }
      gw[(size_t)b * 4 + 0] = (i1 == 0 || i2 == 0) ? p0 : 0.f;
      gw[(size_t)b * 4 + 1] = (i1 == 1 || i2 == 1) ? p1 : 0.f;
      gw[(size_t)b * 4 + 2] = (i1 == 2 || i2 == 2) ? p2 : 0.f;
      gw[(size_t)b * 4 + 3] = (i1 == 3 || i2 == 3) ? p3 : 0.f;
      // pair code (lo,hi): (0,1)->0 (0,2)->1 (0,3)->2 (1,2)->3 (1,3)->4 (2,3)->5
      int lo = min(i1, i2), hi = max(i1, i2);
      pair[b] = (lo == 0) ? (hi - 1) : (lo == 1) ? (hi + 1) : 5;
    }
  } else {
    // ---- We [E][F][P] f32 -> We_T [E][P][F] bf16 ----
    const int tb = (int)blockIdx.x - Bsz;
    const int e  = tb >> 9;
    const int rem = tb & 511;
    const int tf = (rem & 31) * 64;
    const int tp = (rem >> 5) * 64;
    const int t4 = tid * 4;
    const float* src = We + ((size_t)e * NF + tf) * NP + tp;
    #pragma unroll
    for (int i = 0; i < 4; ++i) {
      int li = i * 1024 + t4;
      int r = li >> 6, c = li & 63;
      float4 v = *(const float4*)(src + (size_t)r * NP + c);
      tsh[c][r] = v.x; tsh[c+1][r] = v.y; tsh[c+2][r] = v.z; tsh[c+3][r] = v.w;
    }
    __syncthreads();
    unsigned short* dst = WeT + ((size_t)e * NP + tp) * NF + tf;
    #pragma unroll
    for (int i = 0; i < 4; ++i) {
      int li = i * 1024 + t4;
      int r = li >> 6, c = li & 63;
      ushort4 o;
      o.x = f32_bf16(tsh[r][c]);   o.y = f32_bf16(tsh[r][c+1]);
      o.z = f32_bf16(tsh[r][c+2]); o.w = f32_bf16(tsh[r][c+3]);
      *(ushort4*)(dst + (size_t)r * NF + c) = o;
    }
  }
}

// ---------------- kernel 2: deterministic bucket scan (two-level parallel prefix) ----------
__global__ __launch_bounds__(256) void bucket_scan(
    const int* __restrict__ pair, int* __restrict__ ridx,
    int4* __restrict__ tiletab, int* __restrict__ ntiles,
    double* __restrict__ lossAcc)
{
  __shared__ int cntS[256][6];
  __shared__ int segS[8][6];
  __shared__ int baseS[6];
  const int tid = threadIdx.x;
  int c[6] = {0, 0, 0, 0, 0, 0};
  for (int i = 0; i < 32; ++i) {
    const int code = pair[tid * 32 + i];
    #pragma unroll
    for (int b = 0; b < 6; ++b) c[b] += (code == b) ? 1 : 0;   // static idx (rule #20)
  }
  #pragma unroll
  for (int b = 0; b < 6; ++b) cntS[tid][b] = c[b];
  __syncthreads();
  // level 1: 48 threads, each scans 32 thread-counts of one bucket segment
  if (tid < 48) {
    const int b = tid >> 3, seg = tid & 7;
    int run = 0;
    for (int i = seg * 32; i < seg * 32 + 32; ++i) {
      const int v = cntS[i][b]; cntS[i][b] = run; run += v;
    }
    segS[seg][b] = run;
  }
  __syncthreads();
  // level 2: 6 threads scan the 8 segment sums
  if (tid < 6) {
    int run = 0;
    #pragma unroll
    for (int s = 0; s < 8; ++s) { const int v = segS[s][tid]; segS[s][tid] = run; run += v; }
    baseS[tid] = run;            // bucket total (temporarily)
  }
  __syncthreads();
  if (tid == 0) {
    const int e1t[6] = {0, 0, 0, 1, 1, 2};
    const int e2t[6] = {1, 2, 3, 2, 3, 3};
    int base[6];
    int off = 0, nt = 0;
    for (int b = 0; b < 6; ++b) {
      base[b] = off;
      const int cb = baseS[b];
      for (int i = 0; i < cb; i += BM)
        tiletab[nt++] = make_int4(off + i, min(BM, cb - i), e1t[b], e2t[b]);
      off += cb;
    }
    *ntiles = nt;
    *lossAcc = 0.0;
    #pragma unroll
    for (int b = 0; b < 6; ++b) baseS[b] = base[b];
  }
  __syncthreads();
  int pos[6];
  #pragma unroll
  for (int b = 0; b < 6; ++b) pos[b] = baseS[b] + segS[tid >> 5][b] + cntS[tid][b];
  for (int i = 0; i < 32; ++i) {
    const int r = tid * 32 + i;
    const int code = pair[r];
    #pragma unroll
    for (int b = 0; b < 6; ++b)
      if (code == b) { ridx[pos[b]] = r; ++pos[b]; }
  }
}

// ---------------- kernel 3: dual-expert-B sparse GEMM, depth-3 ring, ONE barrier/iter ------
// Per iter: {vmcnt(own t+1 issues) -> s_barrier -> sched_barrier -> STAGE(t+2) -> COMPUTE(t)}.
// The single barrier proves (a) batch-t loads landed for all waves, (b) all waves finished
// reading buf[(t-1)%3] == the STAGE(t+2) target. Prefetch depth 2 iters.
__global__ __launch_bounds__(512, 4) void moe_gemm_db(
    const unsigned short* __restrict__ fusedB,   // [B][F] bf16, ORIGINAL row order
    const unsigned short* __restrict__ WeT,      // [E][P][F] bf16
    const float* __restrict__ gw,                // [B][4]
    const float* __restrict__ be,                // [E][P]
    const float* __restrict__ label,             // [B][P]
    const int* __restrict__ ntilesP,
    const int4* __restrict__ tiletab,
    const int* __restrict__ ridx,
    float* __restrict__ out,                     // [0]=loss, [1..] preds
    double* __restrict__ lossAcc)
{
  const int bid  = (int)blockIdx.x;
  const int swz  = (bid & 7) * 57 + (bid >> 3);
  const int tile = swz >> 3;
  if (tile >= *ntilesP) return;
  const int pcol = (swz & 7) * 128;

  __shared__ __align__(16) unsigned short As[3][BM * 32];    // 30 KiB
  __shared__ __align__(16) unsigned short B1s[3][128 * 32];  // 24 KiB
  __shared__ __align__(16) unsigned short B2s[3][128 * 32];  // 24 KiB
  __shared__ int   ridxS[BM];
  __shared__ float gwS[BM][2];
  __shared__ float red[8];

  const int4 te     = tiletab[tile];
  const int rowbase = te.x;
  const int vcount  = te.y;
  const int e1      = te.z;
  const int e2      = te.w;

  const int tid  = threadIdx.x;
  const int l    = tid & 63;
  const int wave = tid >> 6;      // 0..7
  const int wr   = wave >> 2;     // 0..1 : rows [wr*80, +80)
  const int wc   = wave & 3;      // 0..3 : cols [wc*32, +32)
  const int lrow = l & 15;
  const int g4   = l >> 4;
  const int schA = (l & 3) ^ ((l >> 3) & 3);   // inverse-swizzled source chunk (lane-const)

  if (tid < BM) {
    const int ri = ridx[rowbase + min(tid, vcount - 1)];
    ridxS[tid]  = ri;
    gwS[tid][0] = gw[(size_t)ri * 4 + e1];
    gwS[tid][1] = gw[(size_t)ri * 4 + e2];
  }
  __syncthreads();

  // gathered global rows for this lane's A staging stripes (16 rows per issue):
  // wave w stages A stripe w; waves 0,1 also stripe 8+w.
  const int rowA0 = ridxS[wave * 16 + (l >> 2)];
  const int rowA1 = (wave < 2) ? ridxS[(8 + wave) * 16 + (l >> 2)] : 0;

  f32x4 acc1[5][2], acc2[5][2];
  #pragma unroll
  for (int m = 0; m < 5; ++m)
    #pragma unroll
    for (int n = 0; n < 2; ++n) {
      acc1[m][n] = f32x4{0.f, 0.f, 0.f, 0.f};
      acc2[m][n] = f32x4{0.f, 0.f, 0.f, 0.f};
    }

  // stage K-step t: 26 issues (10 A + 8 B1 + 8 B2); wave w -> idx {w, w+8, w+16, w+24<26}
  auto STAGE = [&](int t, unsigned short* Ad, unsigned short* B1d, unsigned short* B2d) {
    const int k0 = t << 5;
    const unsigned short* B1g = WeT + ((size_t)e1 * NP + pcol) * NF + k0;
    const unsigned short* B2g = WeT + ((size_t)e2 * NP + pcol) * NF + k0;
    #pragma unroll
    for (int s = 0; s < 4; ++s) {
      const int idx = wave + s * 8;
      if (idx >= 26) continue;
      if (idx < 10) {
        const int r0  = idx * 16;
        const int row = (s == 0) ? rowA0 : rowA1;
        GLOAD16(fusedB + (size_t)row * NF + k0 + schA * 8, (char*)(Ad + r0 * 32));
      } else if (idx < 18) {
        const int r0 = (idx - 10) * 16;
        GLOAD16(B1g + (size_t)(r0 + (l >> 2)) * NF + schA * 8, (char*)(B1d + r0 * 32));
      } else {
        const int r0 = (idx - 18) * 16;
        GLOAD16(B2g + (size_t)(r0 + (l >> 2)) * NF + schA * 8, (char*)(B2d + r0 * 32));
      }
    }
  };

  auto COMPUTE = [&](const unsigned short* Ar, const unsigned short* B1r,
                     const unsigned short* B2r) {
    bf16x8 af[5], b1f[2], b2f[2];
    #pragma unroll
    for (int m = 0; m < 5; ++m) {
      const int fr = wr * 80 + m * 16 + lrow;
      const int ch = (g4 ^ ((fr >> 1) & 3)) * 8;
      af[m] = __builtin_bit_cast(bf16x8, *(const u16x8*)(Ar + fr * 32 + ch));
    }
    #pragma unroll
    for (int n = 0; n < 2; ++n) {
      const int fr = wc * 32 + n * 16 + lrow;
      const int ch = (g4 ^ ((fr >> 1) & 3)) * 8;
      b1f[n] = __builtin_bit_cast(bf16x8, *(const u16x8*)(B1r + fr * 32 + ch));
      b2f[n] = __builtin_bit_cast(bf16x8, *(const u16x8*)(B2r + fr * 32 + ch));
    }
    #pragma unroll
    for (int m = 0; m < 5; ++m)
      #pragma unroll
      for (int n = 0; n < 2; ++n) {
        acc1[m][n] = __builtin_amdgcn_mfma_f32_16x16x32_bf16(af[m], b1f[n], acc1[m][n], 0, 0, 0);
        acc2[m][n] = __builtin_amdgcn_mfma_f32_16x16x32_bf16(af[m], b2f[n], acc2[m][n], 0, 0, 0);
      }
  };

  unsigned short *A0 = As[0],  *A1 = As[1],  *A2 = As[2];
  unsigned short *B10 = B1s[0], *B11 = B1s[1], *B12 = B1s[2];
  unsigned short *B20 = B2s[0], *B21 = B2s[1], *B22 = B2s[2];

  STAGE(0, A0, B10, B20);
  STAGE(1, A1, B11, B21);

  #pragma unroll 1
  for (int t = 0; t < 64; ++t) {
    // per-wave ledger: outstanding newer than batch t = own issues of batch t+1 (4 or 3);
    // STAGE(t+2) is issued only after the barrier. 0 outstanding at t=63.
    if (t == 63)       { asm volatile("s_waitcnt vmcnt(0)" ::: "memory"); }
    else if (wave < 2) { asm volatile("s_waitcnt vmcnt(4)" ::: "memory"); }
    else               { asm volatile("s_waitcnt vmcnt(3)" ::: "memory"); }
    __builtin_amdgcn_s_barrier();          // batch-t landed AND buf[(t-1)%3] free
    __builtin_amdgcn_sched_barrier(0);     // nothing crosses the barrier
    if (t < 62) STAGE(t + 2, A2, B12, B22);
    COMPUTE(A0, B10, B20);
    // rotate ring: next read = A1, next stage target = old A0
    unsigned short* ta = A0; A0 = A1; A1 = A2; A2 = ta;
    unsigned short* t1 = B10; B10 = B11; B11 = B12; B12 = t1;
    unsigned short* t2 = B20; B20 = B21; B21 = B22; B22 = t2;
  }

  // epilogue: pred = w1*(acc1+be1) + w2*(acc2+be2); masked scatter; fused MSE
  float lsum = 0.f;
  #pragma unroll
  for (int m = 0; m < 5; ++m) {
    #pragma unroll
    for (int r = 0; r < 4; ++r) {
      const int lrowi = wr * 80 + m * 16 + g4 * 4 + r;
      const bool valid = lrowi < vcount;
      const int grow = ridxS[lrowi];
      const float w1 = gwS[lrowi][0];
      const float w2 = gwS[lrowi][1];
      #pragma unroll
      for (int n = 0; n < 2; ++n) {
        const int gcol = pcol + wc * 32 + n * 16 + lrow;
        float pred = w1 * (acc1[m][n][r] + be[e1 * NP + gcol])
                   + w2 * (acc2[m][n][r] + be[e2 * NP + gcol]);
        if (valid) {
          out[1 + (size_t)grow * NP + gcol] = pred;
          float d = pred - label[(size_t)grow * NP + gcol];
          lsum += d * d;
        }
      }
    }
  }
  #pragma unroll
  for (int off = 32; off; off >>= 1) lsum += __shfl_xor(lsum, off);
  if (l == 0) red[wave] = lsum;
  __syncthreads();
  if (tid == 0) {
    double s = 0.0;
    #pragma unroll
    for (int w = 0; w < 8; ++w) s += (double)red[w];
    atomicAdd(lossAcc, s);
  }
}

// ---------------- kernel 4: finalize loss ----------------
__global__ void finalize_kernel(const double* __restrict__ lossAcc, float* __restrict__ out) {
  out[0] = (float)(*lossAcc * (1.0 / ((double)Bsz * (double)NP)));
}

extern "C" void kernel_launch(void* const* d_in, const int* in_sizes, int n_in,
                              void* d_out, int out_size, void* d_ws, size_t ws_size,
                              hipStream_t stream) {
  const float* x0    = (const float*)d_in[0];
  const float* x1    = (const float*)d_in[1];
  const float* x2    = (const float*)d_in[2];
  const float* x3    = (const float*)d_in[3];
  const float* label = (const float*)d_in[4];
  const float* Wg    = (const float*)d_in[5];
  const float* We    = (const float*)d_in[6];
  const float* be    = (const float*)d_in[7];
  float* out = (float*)d_out;

  char* ws = (char*)d_ws;
  unsigned short* WeT    = (unsigned short*)ws;                         // 16 MiB
  unsigned short* fusedB = (unsigned short*)(ws + ((size_t)16 << 20));  // 32 MiB
  float*  gw      = (float*)(ws + ((size_t)48 << 20));                  // 128 KiB
  char*   misc    = ws + ((size_t)49 << 20);
  double* lossAcc = (double*)(misc + 0);
  int*    ntiles  = (int*)(misc + 64);
  int4*   tiletab = (int4*)(misc + 256);          // 57 * 16 B
  int*    pair    = (int*)(misc + 4096);          // 32 KiB
  int*    ridx    = (int*)(misc + 4096 + 32768);  // 32 KiB

  gate_fuse<<<dim3(Bsz + 2048), 256, 0, stream>>>(x0, x1, x2, x3, Wg, We, gw, pair, fusedB, WeT);
  bucket_scan<<<dim3(1), 256, 0, stream>>>(pair, ridx, tiletab, ntiles, lossAcc);
  moe_gemm_db<<<dim3(MAXTILES * 8), 512, 0, stream>>>(
      fusedB, WeT, gw, be, label, ntiles, tiletab, ridx, out, lossAcc);
  finalize_kernel<<<1, 1, 0, stream>>>(lossAcc, out);
}

// Round 11
// 138.698 us; speedup vs baseline: 1.0816x; 1.0816x over previous
//
#include <hip/hip_runtime.h>
#include <stdint.h>

#define Bsz  8192
#define DMOD 512
#define NE   4
#define NP   1024
#define NF   2048
#define BM   160
#define MAXTILES 57   // sum_b ceil(cnt_b/160) <= ceil(8192/160)+5 = 57

typedef float  f32x4  __attribute__((ext_vector_type(4)));
typedef __bf16 bf16x8 __attribute__((ext_vector_type(8)));
typedef unsigned short u16x8 __attribute__((ext_vector_type(8)));

typedef __attribute__((address_space(3))) void       lds_void;
typedef const __attribute__((address_space(1))) void glb_void;
#define GLOAD16(gp, lp) \
  __builtin_amdgcn_global_load_lds((glb_void*)(gp), (lds_void*)(lp), 16, 0, 0)

__device__ __forceinline__ unsigned short f32_bf16(float f) {
  unsigned int u = __float_as_uint(f);
  u += 0x7FFFu + ((u >> 16) & 1u);   // round-to-nearest-even
  return (unsigned short)(u >> 16);
}

// ---------------- kernel 1: gate + fusedB write (blocks 0..8191) | We transpose (rest) ------
__global__ __launch_bounds__(256) void gate_fuse(
    const float* __restrict__ x0, const float* __restrict__ x1,
    const float* __restrict__ x2, const float* __restrict__ x3,
    const float* __restrict__ Wg, const float* __restrict__ We,
    float* __restrict__ gw, int* __restrict__ pair,
    unsigned short* __restrict__ fusedB, unsigned short* __restrict__ WeT)
{
  __shared__ float sred[4][4];
  __shared__ float tsh[64][65];
  const int tid = threadIdx.x;

  if ((int)blockIdx.x < Bsz) {
    // ---- gate: logits -> softmax -> top2 -> gw + pair code; also emit bf16 row ----
    const int b = blockIdx.x;
    const int f = tid * 8;
    const float* xm  = (f < 1024) ? (f < 512 ? x0 : x1) : (f < 1536 ? x2 : x3);
    const float* src = xm + (size_t)b * DMOD + (f & 511);
    float4 v0 = *(const float4*)src;
    float4 v1 = *(const float4*)(src + 4);
    u16x8 o;
    o[0] = f32_bf16(v0.x); o[1] = f32_bf16(v0.y); o[2] = f32_bf16(v0.z); o[3] = f32_bf16(v0.w);
    o[4] = f32_bf16(v1.x); o[5] = f32_bf16(v1.y); o[6] = f32_bf16(v1.z); o[7] = f32_bf16(v1.w);
    *(u16x8*)(fusedB + (size_t)b * NF + f) = o;

    float d[4];
    #pragma unroll
    for (int e = 0; e < 4; ++e) {
      const float* w = Wg + e * NF + f;
      d[e] = v0.x * w[0] + v0.y * w[1] + v0.z * w[2] + v0.w * w[3]
           + v1.x * w[4] + v1.y * w[5] + v1.z * w[6] + v1.w * w[7];
    }
    #pragma unroll
    for (int off = 32; off; off >>= 1) {
      #pragma unroll
      for (int e = 0; e < 4; ++e) d[e] += __shfl_xor(d[e], off);
    }
    if ((tid & 63) == 0) {
      #pragma unroll
      for (int e = 0; e < 4; ++e) sred[tid >> 6][e] = d[e];
    }
    __syncthreads();
    if (tid == 0) {
      float a0 = sred[0][0] + sred[1][0] + sred[2][0] + sred[3][0];
      float a1 = sred[0][1] + sred[1][1] + sred[2][1] + sred[3][1];
      float a2 = sred[0][2] + sred[1][2] + sred[2][2] + sred[3][2];
      float a3 = sred[0][3] + sred[1][3] + sred[2][3] + sred[3][3];
      float m  = fmaxf(fmaxf(a0, a1), fmaxf(a2, a3));
      float e0 = expf(a0 - m), e1 = expf(a1 - m), e2 = expf(a2 - m), e3 = expf(a3 - m);
      float inv = 1.f / (e0 + e1 + e2 + e3);
      float p0 = e0 * inv, p1 = e1 * inv, p2 = e2 * inv, p3 = e3 * inv;
      int i1 = 0; float b1 = a0;                 // jax tie-break: strict >
      if (a1 > b1) { b1 = a1; i1 = 1; }
      if (a2 > b1) { b1 = a2; i1 = 2; }
      if (a3 > b1) { b1 = a3; i1 = 3; }
      int i2 = -1; float b2 = -3.4e38f;
      if (i1 != 0 && a0 > b2) { b2 = a0; i2 = 0; }
      if (i1 != 1 && a1 > b2) { b2 = a1; i2 = 1; }
      if (i1 != 2 && a2 > b2) { b2 = a2; i2 = 2; }
      if (i1 != 3 && a3 > b2) { b2 = a3; i2 = 3; }
      gw[(size_t)b * 4 + 0] = (i1 == 0 || i2 == 0) ? p0 : 0.f;
      gw[(size_t)b * 4 + 1] = (i1 == 1 || i2 == 1) ? p1 : 0.f;
      gw[(size_t)b * 4 + 2] = (i1 == 2 || i2 == 2) ? p2 : 0.f;
      gw[(size_t)b * 4 + 3] = (i1 == 3 || i2 == 3) ? p3 : 0.f;
      // pair code (lo,hi): (0,1)->0 (0,2)->1 (0,3)->2 (1,2)->3 (1,3)->4 (2,3)->5
      int lo = min(i1, i2), hi = max(i1, i2);
      pair[b] = (lo == 0) ? (hi - 1) : (lo == 1) ? (hi + 1) : 5;
    }
  } else {
    // ---- We [E][F][P] f32 -> We_T [E][P][F] bf16 ----
    const int tb = (int)blockIdx.x - Bsz;
    const int e  = tb >> 9;
    const int rem = tb & 511;
    const int tf = (rem & 31) * 64;
    const int tp = (rem >> 5) * 64;
    const int t4 = tid * 4;
    const float* src = We + ((size_t)e * NF + tf) * NP + tp;
    #pragma unroll
    for (int i = 0; i < 4; ++i) {
      int li = i * 1024 + t4;
      int r = li >> 6, c = li & 63;
      float4 v = *(const float4*)(src + (size_t)r * NP + c);
      tsh[c][r] = v.x; tsh[c+1][r] = v.y; tsh[c+2][r] = v.z; tsh[c+3][r] = v.w;
    }
    __syncthreads();
    unsigned short* dst = WeT + ((size_t)e * NP + tp) * NF + tf;
    #pragma unroll
    for (int i = 0; i < 4; ++i) {
      int li = i * 1024 + t4;
      int r = li >> 6, c = li & 63;
      ushort4 o;
      o.x = f32_bf16(tsh[r][c]);   o.y = f32_bf16(tsh[r][c+1]);
      o.z = f32_bf16(tsh[r][c+2]); o.w = f32_bf16(tsh[r][c+3]);
      *(ushort4*)(dst + (size_t)r * NF + c) = o;
    }
  }
}

// ---------------- kernel 2: deterministic bucket scan (two-level parallel prefix) ----------
__global__ __launch_bounds__(256) void bucket_scan(
    const int* __restrict__ pair, int* __restrict__ ridx,
    int4* __restrict__ tiletab, int* __restrict__ ntiles,
    double* __restrict__ lossAcc)
{
  __shared__ int cntS[256][6];
  __shared__ int segS[8][6];
  __shared__ int baseS[6];
  const int tid = threadIdx.x;
  int c[6] = {0, 0, 0, 0, 0, 0};
  for (int i = 0; i < 32; ++i) {
    const int code = pair[tid * 32 + i];
    #pragma unroll
    for (int b = 0; b < 6; ++b) c[b] += (code == b) ? 1 : 0;   // static idx (rule #20)
  }
  #pragma unroll
  for (int b = 0; b < 6; ++b) cntS[tid][b] = c[b];
  __syncthreads();
  // level 1: 48 threads, each scans 32 thread-counts of one bucket segment
  if (tid < 48) {
    const int b = tid >> 3, seg = tid & 7;
    int run = 0;
    for (int i = seg * 32; i < seg * 32 + 32; ++i) {
      const int v = cntS[i][b]; cntS[i][b] = run; run += v;
    }
    segS[seg][b] = run;
  }
  __syncthreads();
  // level 2: 6 threads scan the 8 segment sums
  if (tid < 6) {
    int run = 0;
    #pragma unroll
    for (int s = 0; s < 8; ++s) { const int v = segS[s][tid]; segS[s][tid] = run; run += v; }
    baseS[tid] = run;            // bucket total (temporarily)
  }
  __syncthreads();
  if (tid == 0) {
    const int e1t[6] = {0, 0, 0, 1, 1, 2};
    const int e2t[6] = {1, 2, 3, 2, 3, 3};
    int base[6];
    int off = 0, nt = 0;
    for (int b = 0; b < 6; ++b) {
      base[b] = off;
      const int cb = baseS[b];
      for (int i = 0; i < cb; i += BM)
        tiletab[nt++] = make_int4(off + i, min(BM, cb - i), e1t[b], e2t[b]);
      off += cb;
    }
    *ntiles = nt;
    *lossAcc = 0.0;
    #pragma unroll
    for (int b = 0; b < 6; ++b) baseS[b] = base[b];
  }
  __syncthreads();
  int pos[6];
  #pragma unroll
  for (int b = 0; b < 6; ++b) pos[b] = baseS[b] + segS[tid >> 5][b] + cntS[tid][b];
  for (int i = 0; i < 32; ++i) {
    const int r = tid * 32 + i;
    const int code = pair[r];
    #pragma unroll
    for (int b = 0; b < 6; ++b)
      if (code == b) { ridx[pos[b]] = r; ++pos[b]; }
  }
}

// ---------------- kernel 3: dual-expert-B sparse GEMM (r9 verbatim: BK=32, depth-2, ---------
// 2 barriers/iter, counted vmcnt, 55KB LDS -> comfortable 2 blocks/CU; 8 waves, 4/SIMD) ----
__global__ __launch_bounds__(512, 4) void moe_gemm_db(
    const unsigned short* __restrict__ fusedB,   // [B][F] bf16, ORIGINAL row order
    const unsigned short* __restrict__ WeT,      // [E][P][F] bf16
    const float* __restrict__ gw,                // [B][4]
    const float* __restrict__ be,                // [E][P]
    const float* __restrict__ label,             // [B][P]
    const int* __restrict__ ntilesP,
    const int4* __restrict__ tiletab,
    const int* __restrict__ ridx,
    float* __restrict__ out,                     // [0]=loss, [1..] preds
    double* __restrict__ lossAcc)
{
  const int bid  = (int)blockIdx.x;
  const int swz  = (bid & 7) * 57 + (bid >> 3);
  const int tile = swz >> 3;
  if (tile >= *ntilesP) return;
  const int pcol = (swz & 7) * 128;

  __shared__ __align__(16) unsigned short As[2][BM * 32];    // 20 KiB
  __shared__ __align__(16) unsigned short B1s[2][128 * 32];  // 16 KiB
  __shared__ __align__(16) unsigned short B2s[2][128 * 32];  // 16 KiB
  __shared__ int   ridxS[BM];
  __shared__ float gwS[BM][2];
  __shared__ float red[8];

  const int4 te     = tiletab[tile];
  const int rowbase = te.x;
  const int vcount  = te.y;
  const int e1      = te.z;
  const int e2      = te.w;

  const int tid  = threadIdx.x;
  const int l    = tid & 63;
  const int wave = tid >> 6;      // 0..7
  const int wr   = wave >> 2;     // 0..1 : rows [wr*80, +80)
  const int wc   = wave & 3;      // 0..3 : cols [wc*32, +32)
  const int lrow = l & 15;
  const int g4   = l >> 4;
  const int schA = (l & 3) ^ ((l >> 3) & 3);   // inverse-swizzled source chunk (lane-const)

  if (tid < BM) {
    const int ri = ridx[rowbase + min(tid, vcount - 1)];
    ridxS[tid]  = ri;
    gwS[tid][0] = gw[(size_t)ri * 4 + e1];
    gwS[tid][1] = gw[(size_t)ri * 4 + e2];
  }
  __syncthreads();

  // gathered global rows for this lane's A staging stripes (16 rows per issue):
  // wave w stages A stripe w; waves 0,1 also stripe 8+w.
  const int rowA0 = ridxS[wave * 16 + (l >> 2)];
  const int rowA1 = (wave < 2) ? ridxS[(8 + wave) * 16 + (l >> 2)] : 0;

  f32x4 acc1[5][2], acc2[5][2];
  #pragma unroll
  for (int m = 0; m < 5; ++m)
    #pragma unroll
    for (int n = 0; n < 2; ++n) {
      acc1[m][n] = f32x4{0.f, 0.f, 0.f, 0.f};
      acc2[m][n] = f32x4{0.f, 0.f, 0.f, 0.f};
    }

  // stage K-step t: 26 issues (10 A + 8 B1 + 8 B2); wave w -> idx {w, w+8, w+16, w+24<26}
  auto STAGE = [&](int t, int buf) {
    const int k0 = t << 5;
    const unsigned short* B1g = WeT + ((size_t)e1 * NP + pcol) * NF + k0;
    const unsigned short* B2g = WeT + ((size_t)e2 * NP + pcol) * NF + k0;
    #pragma unroll
    for (int s = 0; s < 4; ++s) {
      const int idx = wave + s * 8;
      if (idx >= 26) continue;
      if (idx < 10) {
        const int r0  = idx * 16;
        const int row = (s == 0) ? rowA0 : rowA1;
        GLOAD16(fusedB + (size_t)row * NF + k0 + schA * 8, (char*)(&As[buf][r0 * 32]));
      } else if (idx < 18) {
        const int r0 = (idx - 10) * 16;
        GLOAD16(B1g + (size_t)(r0 + (l >> 2)) * NF + schA * 8, (char*)(&B1s[buf][r0 * 32]));
      } else {
        const int r0 = (idx - 18) * 16;
        GLOAD16(B2g + (size_t)(r0 + (l >> 2)) * NF + schA * 8, (char*)(&B2s[buf][r0 * 32]));
      }
    }
  };

  auto COMPUTE = [&](int buf) {
    bf16x8 af[5], b1f[2], b2f[2];
    #pragma unroll
    for (int m = 0; m < 5; ++m) {
      const int fr = wr * 80 + m * 16 + lrow;
      const int ch = (g4 ^ ((fr >> 1) & 3)) * 8;
      af[m] = __builtin_bit_cast(bf16x8, *(const u16x8*)(&As[buf][fr * 32 + ch]));
    }
    #pragma unroll
    for (int n = 0; n < 2; ++n) {
      const int fr = wc * 32 + n * 16 + lrow;
      const int ch = (g4 ^ ((fr >> 1) & 3)) * 8;
      b1f[n] = __builtin_bit_cast(bf16x8, *(const u16x8*)(&B1s[buf][fr * 32 + ch]));
      b2f[n] = __builtin_bit_cast(bf16x8, *(const u16x8*)(&B2s[buf][fr * 32 + ch]));
    }
    #pragma unroll
    for (int m = 0; m < 5; ++m)
      #pragma unroll
      for (int n = 0; n < 2; ++n) {
        acc1[m][n] = __builtin_amdgcn_mfma_f32_16x16x32_bf16(af[m], b1f[n], acc1[m][n], 0, 0, 0);
        acc2[m][n] = __builtin_amdgcn_mfma_f32_16x16x32_bf16(af[m], b2f[n], acc2[m][n], 0, 0, 0);
      }
  };

  STAGE(0, 0);
  STAGE(1, 1);

  #pragma unroll 1
  for (int t = 0; t < 64; ++t) {
    const int buf = t & 1;
    // per-wave ledger: outstanding newer than batch t = own issues of t+1 (4 or 3); 0 at 63
    if (t == 63)       { asm volatile("s_waitcnt vmcnt(0)" ::: "memory"); }
    else if (wave < 2) { asm volatile("s_waitcnt vmcnt(4)" ::: "memory"); }
    else               { asm volatile("s_waitcnt vmcnt(3)" ::: "memory"); }
    __builtin_amdgcn_s_barrier();          // batch-t loads landed for all waves
    COMPUTE(buf);
    __builtin_amdgcn_sched_barrier(0);     // pin ds_reads+MFMAs before the barrier
    __builtin_amdgcn_s_barrier();          // every wave done reading buf
    if (t < 62) STAGE(t + 2, buf);         // overwrite freed buffer
  }

  // epilogue: pred = w1*(acc1+be1) + w2*(acc2+be2); masked scatter; fused MSE
  float lsum = 0.f;
  #pragma unroll
  for (int m = 0; m < 5; ++m) {
    #pragma unroll
    for (int r = 0; r < 4; ++r) {
      const int lrowi = wr * 80 + m * 16 + g4 * 4 + r;
      const bool valid = lrowi < vcount;
      const int grow = ridxS[lrowi];
      const float w1 = gwS[lrowi][0];
      const float w2 = gwS[lrowi][1];
      #pragma unroll
      for (int n = 0; n < 2; ++n) {
        const int gcol = pcol + wc * 32 + n * 16 + lrow;
        float pred = w1 * (acc1[m][n][r] + be[e1 * NP + gcol])
                   + w2 * (acc2[m][n][r] + be[e2 * NP + gcol]);
        if (valid) {
          out[1 + (size_t)grow * NP + gcol] = pred;
          float d = pred - label[(size_t)grow * NP + gcol];
          lsum += d * d;
        }
      }
    }
  }
  #pragma unroll
  for (int off = 32; off; off >>= 1) lsum += __shfl_xor(lsum, off);
  if (l == 0) red[wave] = lsum;
  __syncthreads();
  if (tid == 0) {
    double s = 0.0;
    #pragma unroll
    for (int w = 0; w < 8; ++w) s += (double)red[w];
    atomicAdd(lossAcc, s);
  }
}

// ---------------- kernel 4: finalize loss ----------------
__global__ void finalize_kernel(const double* __restrict__ lossAcc, float* __restrict__ out) {
  out[0] = (float)(*lossAcc * (1.0 / ((double)Bsz * (double)NP)));
}

extern "C" void kernel_launch(void* const* d_in, const int* in_sizes, int n_in,
                              void* d_out, int out_size, void* d_ws, size_t ws_size,
                              hipStream_t stream) {
  const float* x0    = (const float*)d_in[0];
  const float* x1    = (const float*)d_in[1];
  const float* x2    = (const float*)d_in[2];
  const float* x3    = (const float*)d_in[3];
  const float* label = (const float*)d_in[4];
  const float* Wg    = (const float*)d_in[5];
  const float* We    = (const float*)d_in[6];
  const float* be    = (const float*)d_in[7];
  float* out = (float*)d_out;

  char* ws = (char*)d_ws;
  unsigned short* WeT    = (unsigned short*)ws;                         // 16 MiB
  unsigned short* fusedB = (unsigned short*)(ws + ((size_t)16 << 20));  // 32 MiB
  float*  gw      = (float*)(ws + ((size_t)48 << 20));                  // 128 KiB
  char*   misc    = ws + ((size_t)49 << 20);
  double* lossAcc = (double*)(misc + 0);
  int*    ntiles  = (int*)(misc + 64);
  int4*   tiletab = (int4*)(misc + 256);          // 57 * 16 B
  int*    pair    = (int*)(misc + 4096);          // 32 KiB
  int*    ridx    = (int*)(misc + 4096 + 32768);  // 32 KiB

  gate_fuse<<<dim3(Bsz + 2048), 256, 0, stream>>>(x0, x1, x2, x3, Wg, We, gw, pair, fusedB, WeT);
  bucket_scan<<<dim3(1), 256, 0, stream>>>(pair, ridx, tiletab, ntiles, lossAcc);
  moe_gemm_db<<<dim3(MAXTILES * 8), 512, 0, stream>>>(
      fusedB, WeT, gw, be, label, ntiles, tiletab, ridx, out, lossAcc);
  finalize_kernel<<<1, 1, 0, stream>>>(lossAcc, out);
}